// Round 1
// baseline (971.225 us; speedup 1.0000x reference)
//
#include <hip/hip_runtime.h>

// Elementwise irrep tensor product, output degree 0.
//   out[t, 0:128]   = z0l[t,:] * z0r[t,:]
//   out[t, 128:256] = sum_k z1l[t,k,:] * z1r[t,k,:]   (k = 0..2)
// Memory-bound: 1.074 GB read + 268 MB write -> roofline ~213 us at 6.3 TB/s.
//
// Thread mapping: one thread per float4 of rank (RANK/4 = 32 per token).
// Each thread computes BOTH paths for its float4 slice -> no divergence at
// the 128-column boundary, and all loads/stores are 16 B/lane coalesced.

constexpr int RANK = 128;
constexpr int R4 = RANK / 4;        // 32 float4 per token per path
constexpr int BLOCK = 256;

__global__ __launch_bounds__(BLOCK) void etp_o0_kernel(
    const float4* __restrict__ z0l,
    const float4* __restrict__ z1l,
    const float4* __restrict__ z0r,
    const float4* __restrict__ z1r,
    float4* __restrict__ out,
    int n_threads)              // tokens * R4
{
    int idx = blockIdx.x * BLOCK + threadIdx.x;
    if (idx >= n_threads) return;

    int t = idx >> 5;           // token index
    int j = idx & (R4 - 1);     // float4 index within rank

    // ---- path (0,0,0): scalar * scalar ----
    size_t p0 = (size_t)t * R4 + j;
    float4 a0 = z0l[p0];
    float4 b0 = z0r[p0];
    float4 o0;
    o0.x = a0.x * b0.x;
    o0.y = a0.y * b0.y;
    o0.z = a0.z * b0.z;
    o0.w = a0.w * b0.w;

    // ---- path (1,1,0): dot over irrep dim (3) ----
    size_t p1 = (size_t)t * (3 * R4) + j;
    float4 acc = make_float4(0.f, 0.f, 0.f, 0.f);
#pragma unroll
    for (int k = 0; k < 3; ++k) {
        float4 a = z1l[p1 + (size_t)k * R4];
        float4 b = z1r[p1 + (size_t)k * R4];
        acc.x += a.x * b.x;
        acc.y += a.y * b.y;
        acc.z += a.z * b.z;
        acc.w += a.w * b.w;
    }

    // ---- output: row of 2*RANK floats = 64 float4 ----
    size_t orow = (size_t)t * (2 * R4);
    out[orow + j]      = o0;
    out[orow + R4 + j] = acc;
}

extern "C" void kernel_launch(void* const* d_in, const int* in_sizes, int n_in,
                              void* d_out, int out_size, void* d_ws, size_t ws_size,
                              hipStream_t stream) {
    const float4* z0l = (const float4*)d_in[0];
    const float4* z1l = (const float4*)d_in[1];
    const float4* z0r = (const float4*)d_in[2];
    const float4* z1r = (const float4*)d_in[3];
    float4* out = (float4*)d_out;

    int tokens = in_sizes[0] / RANK;         // 262144
    int n_threads = tokens * R4;             // 8,388,608
    int grid = (n_threads + BLOCK - 1) / BLOCK;

    etp_o0_kernel<<<grid, BLOCK, 0, stream>>>(z0l, z1l, z0r, z1r, out, n_threads);
}